// Round 11
// baseline (486.948 us; speedup 1.0000x reference)
//
#include <hip/hip_runtime.h>
#include <math.h>

#define Bn 4096
#define Tn 512
#define Vn 57
#define En 20
#define Hn 128
#define On 18
#define ROWS 8           // real batch rows per block (M=16 MFMA, 8 pad rows)
#define NTHR 256         // 4 waves; each computes 32 h_new cols (2 col-tiles)
#define NBLK 512         // 2 blocks/CU -> two independent convoys overlap
#define KC 5             // K = 160 = 128 (h) + 20 (emb) + 1 (bias) + 11 pad
#define NKB 20           // k-blocks of 8 halfs
#define BUFH (NKB * 16 * 8)  // 2560 halfs per fragment-major buffer
#define ESTR 40          // embT row stride (halfs)
#define XS 520           // sX row stride (uint16): 8 rows -> distinct banks
#define HFSTR 132        // final-h fp32 row stride

typedef _Float16 half8  __attribute__((ext_vector_type(8)));
typedef _Float16 half4  __attribute__((ext_vector_type(4)));
typedef float    floatx4 __attribute__((ext_vector_type(4)));

__device__ __forceinline__ float fast_tanh(float x) {
    float e = __expf(2.0f * x);
    return 1.0f - __fdividef(2.0f, e + 1.0f);
}

// (256, 2): 2 waves/EU min -> 256-VGPR cap; demand ~115 -> no spill.
// LDS ~28KB/block so TWO blocks co-reside per CU; their independent barriers
// let one block's LDS burst fill the other's serial-chain stall.
__launch_bounds__(NTHR, 2)
__global__ void rnn_mfma_kernel(const int* __restrict__ x,
                                const int* __restrict__ xlen,
                                const float* __restrict__ emb,
                                const float* __restrict__ W_ih,
                                const float* __restrict__ W_hh,
                                const float* __restrict__ b_ih,
                                const float* __restrict__ b_hh,
                                const float* __restrict__ W_out,
                                const float* __restrict__ b_out,
                                float* __restrict__ out)
{
    // Fragment-major B operand: slot = kblock*16 + batch (batch 8..15 mirror 0..7).
    // Wave b128 read = 64 consecutive 16B slots (conflict-free); h-store = 64
    // consecutive 8B half-slots (conflict-free).
    __shared__ __align__(16) _Float16 sB[2][BUFH];
    __shared__ __align__(16) _Float16 sEmb[Vn * ESTR];  // cols 0..19 emb, 20 = 1.0, rest 0
    __shared__ __align__(16) float    sHf[16 * HFSTR];
    __shared__ unsigned short sX[ROWS * XS];            // token ids < 57 fit u16
    __shared__ float sLogit[ROWS][On];
    __shared__ float sMLS[ROWS];

    const int tid = threadIdx.x;
    const int i   = blockIdx.x;
    // pairing remap: co-resident blocks (i,i+256) or (2k,2k+1) both get
    // adjacent row-groups of the length-sorted batch -> equal trip counts.
    const int g    = (i < 256) ? (2 * i) : (2 * (i - 256) + 1);
    const int row0 = g * ROWS;

    const int w    = tid >> 6;       // wave 0..3 -> cols [32w, 32w+32)
    const int lane = tid & 63;
    const int n    = lane & 15;      // MFMA lane idx (batch for B/C, row-in-tile for A)
    const int q    = lane >> 4;      // quad
    const int rb   = n & 7;          // real batch row (8..15 mirror 0..7)

    // ---- A operands (static in VGPRs): W rows 32w+n (tile0) and 32w+16+n (tile1)
    //      of [W_hh | W_ih | bias | 0], fp16 hi-only (R9-validated numerics)
    half8 Ah0[KC], Ah1[KC];
    #pragma unroll
    for (int kc = 0; kc < 4; ++kc) {
        const float* p0 = &W_hh[(32 * w + n) * Hn + kc * 32 + q * 8];
        const float* p1 = &W_hh[(32 * w + 16 + n) * Hn + kc * 32 + q * 8];
        #pragma unroll
        for (int t = 0; t < 8; ++t) {
            Ah0[kc][t] = (_Float16)p0[t];
            Ah1[kc][t] = (_Float16)p1[t];
        }
    }
    {   // kc=4: W_ih cols 0..19, bias at k-col 20, zero beyond
        #pragma unroll
        for (int t = 0; t < 8; ++t) {
            int e = q * 8 + t;
            float v0 = 0.0f, v1 = 0.0f;
            if (e < En) {
                v0 = W_ih[(32 * w + n) * En + e];
                v1 = W_ih[(32 * w + 16 + n) * En + e];
            } else if (e == 20) {
                v0 = b_ih[32 * w + n]      + b_hh[32 * w + n];
                v1 = b_ih[32 * w + 16 + n] + b_hh[32 * w + 16 + n];
            }
            Ah0[4][t] = (_Float16)v0;
            Ah1[4][t] = (_Float16)v1;
        }
    }

    // ---- build embT (fp16) with constant-1 bias column
    for (int idx = tid; idx < Vn * 32; idx += NTHR) {
        int c = idx >> 5, j = idx & 31;
        float v = (j < En) ? emb[c * En + j] : (j == 20 ? 1.0f : 0.0f);
        sEmb[c * ESTR + j] = (_Float16)v;
    }
    // ---- stage token ids as u16 (int4-vectorized reads; 512 % 4 == 0)
    for (int idx = tid * 4; idx < ROWS * Tn; idx += NTHR * 4) {
        int4 v = *(const int4*)&x[row0 * Tn + idx];
        int r = idx >> 9, t = idx & 511;
        unsigned short* p = &sX[r * XS + t];
        p[0] = (unsigned short)v.x;
        p[1] = (unsigned short)v.y;
        p[2] = (unsigned short)v.z;
        p[3] = (unsigned short)v.w;
    }
    // ---- zero both fragment buffers (h0 = 0)
    for (int idx = tid; idx < 2 * BUFH / 8; idx += NTHR)
        ((float4*)sB)[idx] = make_float4(0.f, 0.f, 0.f, 0.f);
    __syncthreads();

    const int Lmax  = xlen[row0];          // sorted desc -> block trip count
    const int len_n = xlen[row0 + rb];

    // ---- xe(0) staging: wave w writes kblock 16+w for all 16 slots (lanes 0..15)
    if (lane < 16) {
        int id0 = (int)sX[rb * XS + 0];
        half8 xe0 = *(const half8*)&sEmb[id0 * ESTR + w * 8];
        *(half8*)&sB[0][(16 + w) * 128 + lane * 8] = xe0;
    }
    __syncthreads();

    float hreg[8] = {0.f, 0.f, 0.f, 0.f, 0.f, 0.f, 0.f, 0.f};

    const int bbase = q * 128 + n * 8;                  // B-read lane base (halfs)
    const int kbA   = 4 * w + (q >> 1);                 // tile0 store kblock
    const int sadr  = kbA * 128 + n * 8 + 4 * (q & 1);  // tile0 store addr (halfs)

    // 2-deep id pipeline (stager lanes): id_use = token at t+1
    int id_use = 0;
    if (lane < 16) id_use = (int)sX[rb * XS + (Lmax > 1 ? 1 : 0)];

    for (int t = 0; t < Lmax; ++t) {
        const _Float16* bp = &sB[t & 1][0];
        _Float16*       np = &sB[(t & 1) ^ 1][0];

        // B operand: 5 b128 reads, 64 consecutive 16B slots each -> conflict-free
        half8 b[KC];
        #pragma unroll
        for (int kc = 0; kc < KC; ++kc)
            b[kc] = *(const half8*)&bp[bbase + kc * 512];

        // xe(t+1) gather from register-carried id (off the MFMA chain)
        half8 xe;
        int id_next = 0;
        if (lane < 16) {
            xe = *(const half8*)&sEmb[id_use * ESTR + w * 8];
            int tnn = (t + 2 < Lmax) ? t + 2 : Lmax - 1;
            id_next = (int)sX[rb * XS + tnn];
        }

        // two col-tiles from one B-read; even/odd accumulator chains per tile
        floatx4 aE0 = {0.f,0.f,0.f,0.f}, aO0 = {0.f,0.f,0.f,0.f};
        floatx4 aE1 = {0.f,0.f,0.f,0.f}, aO1 = {0.f,0.f,0.f,0.f};
        aE0 = __builtin_amdgcn_mfma_f32_16x16x32_f16(Ah0[0], b[0], aE0, 0, 0, 0);
        aE1 = __builtin_amdgcn_mfma_f32_16x16x32_f16(Ah1[0], b[0], aE1, 0, 0, 0);
        aO0 = __builtin_amdgcn_mfma_f32_16x16x32_f16(Ah0[1], b[1], aO0, 0, 0, 0);
        aO1 = __builtin_amdgcn_mfma_f32_16x16x32_f16(Ah1[1], b[1], aO1, 0, 0, 0);
        aE0 = __builtin_amdgcn_mfma_f32_16x16x32_f16(Ah0[2], b[2], aE0, 0, 0, 0);
        aE1 = __builtin_amdgcn_mfma_f32_16x16x32_f16(Ah1[2], b[2], aE1, 0, 0, 0);
        aO0 = __builtin_amdgcn_mfma_f32_16x16x32_f16(Ah0[3], b[3], aO0, 0, 0, 0);
        aO1 = __builtin_amdgcn_mfma_f32_16x16x32_f16(Ah1[3], b[3], aO1, 0, 0, 0);
        aE0 = __builtin_amdgcn_mfma_f32_16x16x32_f16(Ah0[4], b[4], aE0, 0, 0, 0);
        aE1 = __builtin_amdgcn_mfma_f32_16x16x32_f16(Ah1[4], b[4], aE1, 0, 0, 0);

        // C layout: lane(n,q) reg i -> col 32w+4q+i (tile0) / +16 (tile1), batch n
        const bool upd = (t < len_n);
        half4 s0, s1;
        #pragma unroll
        for (int k = 0; k < 4; ++k) {
            float v0 = fast_tanh(aE0[k] + aO0[k]);
            float v1 = fast_tanh(aE1[k] + aO1[k]);
            hreg[k]     = upd ? v0 : hreg[k];
            hreg[4 + k] = upd ? v1 : hreg[4 + k];
            s0[k] = (_Float16)hreg[k];
            s1[k] = (_Float16)hreg[4 + k];
        }
        *(half4*)&np[sadr]       = s0;   // consecutive 8B half-slots -> conflict-free
        *(half4*)&np[sadr + 256] = s1;
        if (lane < 16)
            *(half8*)&np[(16 + w) * 128 + lane * 8] = xe;

        id_use = id_next;
        __syncthreads();   // per-block barrier; the co-resident block fills the stall
    }

    // ---- publish final fp32 h (16 slots; rows 8..15 are mirrors, ignored)
    {
        float4 f0, f1;
        f0.x = hreg[0]; f0.y = hreg[1]; f0.z = hreg[2]; f0.w = hreg[3];
        f1.x = hreg[4]; f1.y = hreg[5]; f1.z = hreg[6]; f1.w = hreg[7];
        *(float4*)&sHf[n * HFSTR + 32 * w + 4 * q]      = f0;
        *(float4*)&sHf[n * HFSTR + 32 * w + 16 + 4 * q] = f1;
    }
    __syncthreads();

    // ---- epilogue: logits = relu(h) @ W_out^T + b_out, then log_softmax
    if (tid < ROWS * On) {
        int r = tid / On, c = tid % On;
        float acc = b_out[c];
        for (int k = 0; k < Hn; ++k) {
            float hv = sHf[r * HFSTR + k];
            hv = hv > 0.0f ? hv : 0.0f;
            acc = fmaf(hv, W_out[c * Hn + k], acc);
        }
        sLogit[r][c] = acc;
    }
    __syncthreads();

    if (tid < ROWS) {
        float m = -INFINITY;
        #pragma unroll
        for (int c = 0; c < On; ++c) m = fmaxf(m, sLogit[tid][c]);
        float s = 0.0f;
        #pragma unroll
        for (int c = 0; c < On; ++c) s += __expf(sLogit[tid][c] - m);
        sMLS[tid] = m + __logf(s);
    }
    __syncthreads();

    if (tid < ROWS * On) {
        int r = tid / On, c = tid % On;
        out[(row0 + r) * On + c] = sLogit[r][c] - sMLS[r];
    }
}

extern "C" void kernel_launch(void* const* d_in, const int* in_sizes, int n_in,
                              void* d_out, int out_size, void* d_ws, size_t ws_size,
                              hipStream_t stream) {
    const int*   x     = (const int*)d_in[0];
    const int*   xlen  = (const int*)d_in[1];
    const float* emb   = (const float*)d_in[2];
    const float* W_ih  = (const float*)d_in[3];
    const float* W_hh  = (const float*)d_in[4];
    const float* b_ih  = (const float*)d_in[5];
    const float* b_hh  = (const float*)d_in[6];
    const float* W_out = (const float*)d_in[7];
    const float* b_out = (const float*)d_in[8];
    float*       out   = (float*)d_out;

    rnn_mfma_kernel<<<NBLK, NTHR, 0, stream>>>(x, xlen, emb, W_ih, W_hh,
                                               b_ih, b_hh, W_out, b_out, out);
}

// Round 13
// 233.848 us; speedup vs baseline: 2.0823x; 2.0823x over previous
//
#include <hip/hip_runtime.h>
#include <math.h>

#define Bn 4096
#define Tn 512
#define Vn 57
#define En 20
#define Hn 128
#define On 18
#define ROWS 16          // batch rows per block (= MFMA N)
#define NTHR 512         // 8 waves (2/SIMD), one 16-col tile each
#define NBLK (Bn / ROWS) // 256 blocks -> 1 per CU (static LDS > 80KB, volatile-kept)
#define KC 5             // K = 160 = 128 (h) + 20 (emb) + 1 (bias) + 11 pad
#define NKB 20           // k-blocks of 8 halfs
#define BUFH (NKB * 16 * 8)  // 2560 halfs per fragment-major buffer
#define ESTR 40          // embT row stride (halfs)
#define XSTR 513         // staged x row stride (ints): bank=(r+t)%32, conflict-free
#define HFSTR 132        // final-h fp32 row stride
#define ASCALE 2.8853900817779268f   // 2*log2(e): folds tanh's 2x and log2e mul into A

typedef _Float16 half8  __attribute__((ext_vector_type(8)));
typedef _Float16 half4  __attribute__((ext_vector_type(4)));
typedef __fp16   fp16x2 __attribute__((ext_vector_type(2)));   // cvt_pkrtz native type
typedef float    floatx4 __attribute__((ext_vector_type(4)));

// acc is pre-scaled by 2*log2e: tanh(x) = 1 - 2/(1+2^(2x*log2e))
__device__ __forceinline__ float tanh_scaled(float z) {
    float e = __builtin_amdgcn_exp2f(z);          // v_exp_f32
    float r = __builtin_amdgcn_rcpf(e + 1.0f);    // v_rcp_f32
    return fmaf(-2.0f, r, 1.0f);
}

__device__ __forceinline__ unsigned pk_u32(fp16x2 v) {
    union { fp16x2 h; unsigned u; } c; c.h = v; return c.u;
}

// (512, 2): 8 waves = 2/EU -> VGPR cap 256; demand ~70 -> no spill, full hiding.
__launch_bounds__(NTHR, 2)
__global__ void rnn_mfma_kernel(const int* __restrict__ x,
                                const int* __restrict__ xlen,
                                const float* __restrict__ emb,
                                const float* __restrict__ W_ih,
                                const float* __restrict__ W_hh,
                                const float* __restrict__ b_ih,
                                const float* __restrict__ b_hh,
                                const float* __restrict__ W_out,
                                const float* __restrict__ b_out,
                                float* __restrict__ out)
{
    // Fragment-major B operand: slot s = kblock*16 + batch_row holds halfs
    // [kblock*8 .. +8) of that row. Wave b128 read = 64 consecutive slots
    // (conflict-free); h-store = 64 consecutive 8B half-slots (conflict-free).
    __shared__ __align__(16) _Float16 sB[2][BUFH];
    __shared__ __align__(16) _Float16 sEmb[Vn * ESTR];  // cols 0..19 emb, 20 = 1.0, rest 0
    __shared__ __align__(16) float    sHf[ROWS * HFSTR];
    __shared__ int sX[ROWS * XSTR];
    __shared__ float sLogit[ROWS][On];
    __shared__ float sMLS[ROWS];
    __shared__ float sPad[6200];   // 24.8KB pad: total ~82KB -> exactly 1 block/CU

    const int tid  = threadIdx.x;
    const int blk  = blockIdx.x;
    const int row0 = blk * ROWS;

    // volatile touch keeps sPad (and the 1-block/CU LDS footprint) alive
    ((volatile float*)sPad)[tid % 6200] = 0.0f;

    const int w    = tid >> 6;       // wave 0..7 -> cols [16w, 16w+16)
    const int lane = tid & 63;
    const int n    = lane & 15;      // MFMA lane index (batch for B/C, row-in-tile for A)
    const int q    = lane >> 4;      // quad
    const bool stager = (w >= 4) && (lane < 16);   // waves 4..7 stage xe kblock 16+(w-4)
    const int  wk     = (w >= 4) ? (w - 4) : 0;

    // ---- A operand (static): rows 16w+n of [W_hh | W_ih | bias | 0], fp16,
    //      pre-scaled by 2*log2e (tanh input fusion)
    half8 Ah[KC];
    #pragma unroll
    for (int kc = 0; kc < 4; ++kc) {
        const float* p = &W_hh[(16 * w + n) * Hn + kc * 32 + q * 8];
        #pragma unroll
        for (int i = 0; i < 8; ++i)
            Ah[kc][i] = (_Float16)(p[i] * ASCALE);
    }
    {   // kc=4: W_ih cols 0..19, bias at k-col 20, zero beyond
        #pragma unroll
        for (int i = 0; i < 8; ++i) {
            int e = q * 8 + i;
            float v = 0.0f;
            if (e < En)       v = W_ih[(16 * w + n) * En + e];
            else if (e == 20) v = b_ih[16 * w + n] + b_hh[16 * w + n];
            Ah[4][i] = (_Float16)(v * ASCALE);
        }
    }

    // ---- build embT (fp16) with constant-1 bias column
    for (int idx = tid; idx < Vn * 32; idx += NTHR) {
        int c = idx >> 5, j = idx & 31;
        float v = (j < En) ? emb[c * En + j] : (j == 20 ? 1.0f : 0.0f);
        sEmb[c * ESTR + j] = (_Float16)v;
    }
    // ---- stage vocab ids (int4-vectorized; 512 % 4 == 0 -> no row crossing)
    for (int idx = tid * 4; idx < ROWS * Tn; idx += NTHR * 4) {
        int4 v = *(const int4*)&x[row0 * Tn + idx];
        int r = idx >> 9, t = idx & 511;
        sX[r * XSTR + t]     = v.x;
        sX[r * XSTR + t + 1] = v.y;
        sX[r * XSTR + t + 2] = v.z;
        sX[r * XSTR + t + 3] = v.w;
    }
    // ---- zero both fragment buffers (h0 = 0)
    for (int idx = tid; idx < 2 * BUFH / 8; idx += NTHR)
        ((float4*)sB)[idx] = make_float4(0.f, 0.f, 0.f, 0.f);
    __syncthreads();

    const int Lmax  = xlen[row0];    // sorted descending -> block trip count
    const int len_n = xlen[row0 + n];

    // ---- xe(0) staging (waves 4..7, lanes 0..15)
    if (stager) {
        int id0 = sX[lane * XSTR + 0];
        half8 xe0 = *(const half8*)&sEmb[id0 * ESTR + wk * 8];
        *(half8*)&sB[0][(16 + wk) * 128 + lane * 8] = xe0;
    }
    __syncthreads();

    float hreg[4] = {0.f, 0.f, 0.f, 0.f};

    const int bbase = q * 128 + n * 8;                       // B-read lane base (halfs)
    const int kbA   = 2 * w + (q >> 1);                      // h-store kblock
    const int sadr  = kbA * 128 + n * 8 + 4 * (q & 1);       // h-store addr (halfs)

    // two-step id pipeline (staging waves only): id_use = token at t+1
    int id_use = 0;
    if (stager) id_use = sX[lane * XSTR + (Lmax > 1 ? 1 : 0)];

    // one step: src/dst buffers are compile-time-selected (t unrolled by 2),
    // killing per-iteration pointer-select VALU
    #define RNN_STEP(bp, np, t)                                                   \
    {                                                                             \
        half8 b[KC];                                                              \
        _Pragma("unroll")                                                         \
        for (int kc = 0; kc < KC; ++kc)                                           \
            b[kc] = *(const half8*)&(bp)[bbase + kc * 512];                       \
        half8 xe;                                                                 \
        int id_next = 0;                                                          \
        if (stager) {                                                             \
            xe = *(const half8*)&sEmb[id_use * ESTR + wk * 8];                    \
            id_next = sX[lane * XSTR + min((t) + 2, Lmax - 1)];                   \
        }                                                                         \
        floatx4 aE = {0.f, 0.f, 0.f, 0.f};                                        \
        floatx4 aO = {0.f, 0.f, 0.f, 0.f};                                        \
        aE = __builtin_amdgcn_mfma_f32_16x16x32_f16(Ah[0], b[0], aE, 0, 0, 0);    \
        aO = __builtin_amdgcn_mfma_f32_16x16x32_f16(Ah[1], b[1], aO, 0, 0, 0);    \
        aE = __builtin_amdgcn_mfma_f32_16x16x32_f16(Ah[2], b[2], aE, 0, 0, 0);    \
        aO = __builtin_amdgcn_mfma_f32_16x16x32_f16(Ah[3], b[3], aO, 0, 0, 0);    \
        aE = __builtin_amdgcn_mfma_f32_16x16x32_f16(Ah[4], b[4], aE, 0, 0, 0);    \
        const bool upd = ((t) < len_n);                                           \
        _Pragma("unroll")                                                         \
        for (int i = 0; i < 4; ++i) {                                             \
            float v = tanh_scaled(aE[i] + aO[i]);                                 \
            hreg[i] = upd ? v : hreg[i];                                          \
        }                                                                         \
        fp16x2 p0 = __builtin_amdgcn_cvt_pkrtz(hreg[0], hreg[1]);                 \
        fp16x2 p1 = __builtin_amdgcn_cvt_pkrtz(hreg[2], hreg[3]);                 \
        uint2 pk; pk.x = pk_u32(p0); pk.y = pk_u32(p1);                           \
        *(uint2*)&(np)[sadr] = pk;                                                \
        if (stager)                                                               \
            *(half8*)&(np)[(16 + wk) * 128 + lane * 8] = xe;                      \
        id_use = id_next;                                                         \
        __syncthreads();                                                          \
    }

    int t = 0;
    for (; t + 2 <= Lmax; t += 2) {
        RNN_STEP(&sB[0][0], &sB[1][0], t);
        RNN_STEP(&sB[1][0], &sB[0][0], t + 1);
    }
    if (t < Lmax) {
        RNN_STEP(&sB[0][0], &sB[1][0], t);
    }
    #undef RNN_STEP

    // ---- publish final fp32 h
    {
        float4 f0;
        f0.x = hreg[0]; f0.y = hreg[1]; f0.z = hreg[2]; f0.w = hreg[3];
        *(float4*)&sHf[n * HFSTR + 16 * w + 4 * q] = f0;
    }
    __syncthreads();

    // ---- epilogue: logits = relu(h) @ W_out^T + b_out, then log_softmax
    for (int it = tid; it < ROWS * On; it += NTHR) {
        int r = it / On, c = it % On;
        float acc = b_out[c];
        for (int k = 0; k < Hn; ++k) {
            float hv = sHf[r * HFSTR + k];
            hv = hv > 0.0f ? hv : 0.0f;
            acc = fmaf(hv, W_out[c * Hn + k], acc);
        }
        sLogit[r][c] = acc;
    }
    __syncthreads();

    if (tid < ROWS) {
        float m = -INFINITY;
        #pragma unroll
        for (int c = 0; c < On; ++c) m = fmaxf(m, sLogit[tid][c]);
        float s = 0.0f;
        #pragma unroll
        for (int c = 0; c < On; ++c) s += __expf(sLogit[tid][c] - m);
        sMLS[tid] = m + __logf(s);
    }
    __syncthreads();

    for (int it = tid; it < ROWS * On; it += NTHR) {
        int r = it / On, c = it % On;
        out[(row0 + r) * On + c] = sLogit[r][c] - sMLS[r];
    }
}

extern "C" void kernel_launch(void* const* d_in, const int* in_sizes, int n_in,
                              void* d_out, int out_size, void* d_ws, size_t ws_size,
                              hipStream_t stream) {
    const int*   x     = (const int*)d_in[0];
    const int*   xlen  = (const int*)d_in[1];
    const float* emb   = (const float*)d_in[2];
    const float* W_ih  = (const float*)d_in[3];
    const float* W_hh  = (const float*)d_in[4];
    const float* b_ih  = (const float*)d_in[5];
    const float* b_hh  = (const float*)d_in[6];
    const float* W_out = (const float*)d_in[7];
    const float* b_out = (const float*)d_in[8];
    float*       out   = (float*)d_out;

    rnn_mfma_kernel<<<NBLK, NTHR, 0, stream>>>(x, xlen, emb, W_ih, W_hh,
                                               b_ih, b_hh, W_out, b_out, out);
}